// Round 1
// baseline (438.444 us; speedup 1.0000x reference)
//
#include <hip/hip_runtime.h>
#include <math.h>

#define S_ 64
#define E_ 2048
#define H_ 32
#define D_ 64
#define L_ 2048
#define BS_ 16
#define BPS_ 128
#define QKV_N (3 * E_)   // 6144

// ---------------------------------------------------------------------------
// Tall-skinny GEMM: C[64,N] += A[64,K] @ B[K,N]  (+ bias, added by k-chunk 0)
// grid = (N/64, KSPLIT); block = 256. Each thread: 1 column, 16 m-rows.
// A tile staged in LDS, read via wave-uniform broadcast (no bank conflicts).
// C must be zeroed before launch (atomicAdd accumulation across k-chunks).
// ---------------------------------------------------------------------------
__global__ __launch_bounds__(256) void gemm64(const float* __restrict__ A,
                                              const float* __restrict__ B,
                                              const float* __restrict__ bias,
                                              float* __restrict__ C,
                                              int K, int N) {
    __shared__ float As[64][32];
    const int t   = threadIdx.x;
    const int col = blockIdx.x * 64 + (t & 63);
    const int mg  = t >> 6;                 // 0..3, owns m = mg*16 .. mg*16+15
    const int kchunk = K / gridDim.y;
    const int ks  = blockIdx.y * kchunk;

    float acc[16];
    const float binit = (blockIdx.y == 0) ? bias[col] : 0.f;
#pragma unroll
    for (int mm = 0; mm < 16; ++mm) acc[mm] = binit;

    for (int k0 = ks; k0 < ks + kchunk; k0 += 32) {
        __syncthreads();
#pragma unroll
        for (int i = 0; i < 8; ++i) {
            int idx = t + i * 256;          // 2048 elements = 64 x 32
            As[idx >> 5][idx & 31] = A[(size_t)(idx >> 5) * K + k0 + (idx & 31)];
        }
        __syncthreads();
#pragma unroll 4
        for (int kk = 0; kk < 32; ++kk) {
            float w = B[(size_t)(k0 + kk) * N + col];
#pragma unroll
            for (int mm = 0; mm < 16; ++mm)
                acc[mm] = fmaf(As[mg * 16 + mm][kk], w, acc[mm]);
        }
    }
#pragma unroll
    for (int mm = 0; mm < 16; ++mm)
        atomicAdd(&C[(size_t)(mg * 16 + mm) * N + col], acc[mm]);
}

// ---------------------------------------------------------------------------
// Paged decode attention. One block per (seq, head); 4 waves per block.
// Wave iteration = one 16-token cache block: lane = g*4+j, g=token(0..15),
// j=quarter(0..3). Lane loads 16 floats of K/V as 4x float4 at
// tok_base + i*16 + j*4  -> each 4-lane group covers contiguous 64 B.
// Online softmax per wave; merge 4 waves via LDS.
// ---------------------------------------------------------------------------
__global__ __launch_bounds__(256) void paged_attn(
        const float* __restrict__ qkv,
        const float* __restrict__ kcache,
        const float* __restrict__ vcache,
        const int* __restrict__ btab,
        const int* __restrict__ clens,
        float* __restrict__ attn) {
    const int bid  = blockIdx.x;
    const int s    = bid >> 5;          // seq
    const int h    = bid & 31;          // head
    const int t    = threadIdx.x;
    const int w    = t >> 6;            // wave 0..3
    const int lane = t & 63;
    const int g    = lane >> 2;         // token slot within cache block
    const int j    = lane & 3;          // quarter of head_dim
    const int ctx  = clens[s];
    const int nb   = (ctx + 15) >> 4;   // cache blocks to process (>=64)
    const float scale = 0.125f;         // 1/sqrt(64)

    // q fragment: element d = i*16 + j*4 + c
    const float* qp = qkv + (size_t)s * QKV_N + h * 64;
    float4 q4[4];
#pragma unroll
    for (int i = 0; i < 4; ++i)
        q4[i] = *(const float4*)(qp + i * 16 + j * 4);

    float m = -INFINITY, l = 0.f;
    float4 acc[4];
#pragma unroll
    for (int i = 0; i < 4; ++i) acc[i] = make_float4(0.f, 0.f, 0.f, 0.f);

    for (int b = w; b < nb; b += 4) {
        const int blk = btab[s * BPS_ + b];
        const int tok = b * 16 + g;
        const size_t base = ((size_t)blk * BS_ + g) * (H_ * D_) + h * 64;

        const float* kp = kcache + base;
        float4 k4[4];
#pragma unroll
        for (int i = 0; i < 4; ++i)
            k4[i] = *(const float4*)(kp + i * 16 + j * 4);

        float part = 0.f;
#pragma unroll
        for (int i = 0; i < 4; ++i)
            part += q4[i].x * k4[i].x + q4[i].y * k4[i].y +
                    q4[i].z * k4[i].z + q4[i].w * k4[i].w;
        part += __shfl_xor(part, 1);
        part += __shfl_xor(part, 2);

        float score = (tok < ctx) ? part * scale : -INFINITY;

        float mx = score;
        mx = fmaxf(mx, __shfl_xor(mx, 4));
        mx = fmaxf(mx, __shfl_xor(mx, 8));
        mx = fmaxf(mx, __shfl_xor(mx, 16));
        mx = fmaxf(mx, __shfl_xor(mx, 32));

        if (mx > m) {                   // wave-uniform; rare after warmup
            float r = expf(m - mx);     // first iter: exp(-inf)=0 zeroes acc/l
            l *= r;
#pragma unroll
            for (int i = 0; i < 4; ++i) {
                acc[i].x *= r; acc[i].y *= r; acc[i].z *= r; acc[i].w *= r;
            }
            m = mx;
        }

        float p = expf(score - m);      // invalid token -> exp(-inf) = 0
        float sp = p;
        sp += __shfl_xor(sp, 4);
        sp += __shfl_xor(sp, 8);
        sp += __shfl_xor(sp, 16);
        sp += __shfl_xor(sp, 32);
        l += sp;

        const float* vp = vcache + base;
#pragma unroll
        for (int i = 0; i < 4; ++i) {
            float4 v4 = *(const float4*)(vp + i * 16 + j * 4);
            acc[i].x = fmaf(p, v4.x, acc[i].x);
            acc[i].y = fmaf(p, v4.y, acc[i].y);
            acc[i].z = fmaf(p, v4.z, acc[i].z);
            acc[i].w = fmaf(p, v4.w, acc[i].w);
        }
    }

    // current token's K/V (position L, always attended) -- wave 0 only
    if (w == 0) {
        const float* kn = qkv + (size_t)s * QKV_N + E_ + h * 64;
        const float* vn = qkv + (size_t)s * QKV_N + 2 * E_ + h * 64;
        float4 k4[4];
#pragma unroll
        for (int i = 0; i < 4; ++i)
            k4[i] = *(const float4*)(kn + i * 16 + j * 4);
        float part = 0.f;
#pragma unroll
        for (int i = 0; i < 4; ++i)
            part += q4[i].x * k4[i].x + q4[i].y * k4[i].y +
                    q4[i].z * k4[i].z + q4[i].w * k4[i].w;
        part += __shfl_xor(part, 1);
        part += __shfl_xor(part, 2);
        float score = part * scale;     // identical on all 64 lanes
        if (score > m) {
            float r = expf(m - score);
            l *= r;
#pragma unroll
            for (int i = 0; i < 4; ++i) {
                acc[i].x *= r; acc[i].y *= r; acc[i].z *= r; acc[i].w *= r;
            }
            m = score;
        }
        float p = expf(score - m);
        l += p;                         // single token, counted once
        if (g == 0) {                   // exactly one token-group contributes
#pragma unroll
            for (int i = 0; i < 4; ++i) {
                float4 v4 = *(const float4*)(vn + i * 16 + j * 4);
                acc[i].x = fmaf(p, v4.x, acc[i].x);
                acc[i].y = fmaf(p, v4.y, acc[i].y);
                acc[i].z = fmaf(p, v4.z, acc[i].z);
                acc[i].w = fmaf(p, v4.w, acc[i].w);
            }
        }
    }

    // reduce acc across the 16 token-groups (lane-index bits 2..5)
#pragma unroll
    for (int i = 0; i < 4; ++i) {
#pragma unroll
        for (int msk = 4; msk <= 32; msk <<= 1) {
            acc[i].x += __shfl_xor(acc[i].x, msk);
            acc[i].y += __shfl_xor(acc[i].y, msk);
            acc[i].z += __shfl_xor(acc[i].z, msk);
            acc[i].w += __shfl_xor(acc[i].w, msk);
        }
    }

    __shared__ float lm[4], ll[4], la[4][64];
    if (g == 0) {                       // lanes 0..3 hold the wave's 64 floats
#pragma unroll
        for (int i = 0; i < 4; ++i) {
            la[w][i * 16 + j * 4 + 0] = acc[i].x;
            la[w][i * 16 + j * 4 + 1] = acc[i].y;
            la[w][i * 16 + j * 4 + 2] = acc[i].z;
            la[w][i * 16 + j * 4 + 3] = acc[i].w;
        }
    }
    if (lane == 0) { lm[w] = m; ll[w] = l; }
    __syncthreads();

    if (t < 64) {
        const int d = t;
        float M = fmaxf(fmaxf(lm[0], lm[1]), fmaxf(lm[2], lm[3]));
        float Lsum = 0.f, o = 0.f;
#pragma unroll
        for (int ww = 0; ww < 4; ++ww) {
            float f = expf(lm[ww] - M);
            Lsum += f * ll[ww];
            o += f * la[ww][d];
        }
        attn[(size_t)s * E_ + h * 64 + d] = o / Lsum;
    }
}

// ---------------------------------------------------------------------------
extern "C" void kernel_launch(void* const* d_in, const int* in_sizes, int n_in,
                              void* d_out, int out_size, void* d_ws, size_t ws_size,
                              hipStream_t stream) {
    const float* hidden = (const float*)d_in[0];
    const float* wqkv   = (const float*)d_in[1];
    const float* bqkv   = (const float*)d_in[2];
    const float* wout   = (const float*)d_in[3];
    const float* bout   = (const float*)d_in[4];
    const float* kcache = (const float*)d_in[5];
    const float* vcache = (const float*)d_in[6];
    const int*   btab   = (const int*)d_in[7];
    const int*   clens  = (const int*)d_in[8];
    float* out = (float*)d_out;

    float* qkv     = (float*)d_ws;                    // [64, 6144]
    float* attnbuf = qkv + (size_t)S_ * QKV_N;        // [64, 2048]

    // zero accumulation targets (harness poisons buffers; atomicAdd needs 0)
    hipMemsetAsync(qkv, 0, (size_t)S_ * QKV_N * sizeof(float), stream);
    hipMemsetAsync(out, 0, (size_t)S_ * E_ * sizeof(float), stream);

    // 1) fused QKV projection: [64,2048] x [2048,6144] + bias
    gemm64<<<dim3(QKV_N / 64, 8), 256, 0, stream>>>(hidden, wqkv, bqkv, qkv,
                                                    E_, QKV_N);
    // 2) paged attention -> attnbuf [64, 2048]
    paged_attn<<<dim3(S_ * H_), 256, 0, stream>>>(qkv, kcache, vcache, btab,
                                                  clens, attnbuf);
    // 3) output projection: [64,2048] x [2048,2048] + bias -> d_out
    gemm64<<<dim3(E_ / 64, 16), 256, 0, stream>>>(attnbuf, wout, bout, out,
                                                  E_, E_);
}